// Round 3
// baseline (1872.435 us; speedup 1.0000x reference)
//
#include <hip/hip_runtime.h>

#define RES   32
#define NVOX  (RES * RES * RES)   // 32768
#define NB    8
#define NC    64
#define NPTS  100000

// workspace layout in 4-byte words
#define SUM_OFF  0                               // 24 floats (pad 32)
#define RAD_OFF  32                              // 8 uints (pad 32)
#define CNT_OFF  64                              // NB*NVOX ints
#define OFFS_OFF (CNT_OFF  + NB * NVOX)          // NB*NVOX ints
#define CURS_OFF (OFFS_OFF + NB * NVOX)          // NB*NVOX ints
#define IDX_OFF  (CURS_OFF + NB * NVOX)          // NB*NPTS ints (per-point voxel)
#define PERM_OFF (IDX_OFF  + NB * NPTS)          // NB*NPTS ints (n->pos or pos->n)
#define VOX_OFF  (PERM_OFF + NB * NPTS)          // NB*NPTS uint16 = NB*NPTS/2 words
#define FS_OFF   (VOX_OFF  + NB * NPTS / 2)      // featS (mode-dependent size)

// ---------------------------------------------------------------------------
// Kernel 1: per-batch sum of coords -> ws_sum[b*3+k]
// ---------------------------------------------------------------------------
__global__ void sum_kernel(const float* __restrict__ coords,
                           float* __restrict__ ws_sum) {
    const int b = blockIdx.y;
    const float* cb = coords + (size_t)b * 3 * NPTS;
    float s0 = 0.f, s1 = 0.f, s2 = 0.f;
    for (int n = blockIdx.x * blockDim.x + threadIdx.x; n < NPTS;
         n += blockDim.x * gridDim.x) {
        s0 += cb[n];
        s1 += cb[NPTS + n];
        s2 += cb[2 * NPTS + n];
    }
    for (int off = 32; off > 0; off >>= 1) {
        s0 += __shfl_down(s0, off, 64);
        s1 += __shfl_down(s1, off, 64);
        s2 += __shfl_down(s2, off, 64);
    }
    if ((threadIdx.x & 63) == 0) {
        atomicAdd(&ws_sum[b * 3 + 0], s0);
        atomicAdd(&ws_sum[b * 3 + 1], s1);
        atomicAdd(&ws_sum[b * 3 + 2], s2);
    }
}

// ---------------------------------------------------------------------------
// Kernel 2: per-batch max squared radius -> ws_rad[b] (uint bits, monotone)
// ---------------------------------------------------------------------------
__global__ void rad_kernel(const float* __restrict__ coords,
                           const float* __restrict__ ws_sum,
                           unsigned int* __restrict__ ws_rad) {
#pragma clang fp contract(off)
    const int b = blockIdx.y;
    const float* cb = coords + (size_t)b * 3 * NPTS;
    const float m0 = ws_sum[b * 3 + 0] / (float)NPTS;
    const float m1 = ws_sum[b * 3 + 1] / (float)NPTS;
    const float m2 = ws_sum[b * 3 + 2] / (float)NPTS;
    float mx = 0.f;
    for (int n = blockIdx.x * blockDim.x + threadIdx.x; n < NPTS;
         n += blockDim.x * gridDim.x) {
        float dx = cb[n] - m0;
        float dy = cb[NPTS + n] - m1;
        float dz = cb[2 * NPTS + n] - m2;
        float sq = dx * dx + dy * dy + dz * dz;
        mx = fmaxf(mx, sq);
    }
    for (int off = 32; off > 0; off >>= 1)
        mx = fmaxf(mx, __shfl_down(mx, off, 64));
    if ((threadIdx.x & 63) == 0)
        atomicMax(&ws_rad[b], __float_as_uint(mx));
}

// ---------------------------------------------------------------------------
// Kernel 3: per point: norm coords (output 1), voxel idx, histogram
// ---------------------------------------------------------------------------
__global__ void index_kernel(const float* __restrict__ coords,
                             const float* __restrict__ ws_sum,
                             const unsigned int* __restrict__ ws_rad,
                             float* __restrict__ norm_out,
                             int* __restrict__ idx_arr,
                             int* __restrict__ counts) {
#pragma clang fp contract(off)
    const int n = blockIdx.x * blockDim.x + threadIdx.x;
    const int b = blockIdx.y;
    if (n >= NPTS) return;

    const float m0 = ws_sum[b * 3 + 0] / (float)NPTS;
    const float m1 = ws_sum[b * 3 + 1] / (float)NPTS;
    const float m2 = ws_sum[b * 3 + 2] / (float)NPTS;
    const float r  = sqrtf(__uint_as_float(ws_rad[b]));
    const float d  = r * 2.0f;   // EPS == 0

    const float* cb = coords + (size_t)b * 3 * NPTS;
    const float x = cb[n] - m0;
    const float y = cb[NPTS + n] - m1;
    const float z = cb[2 * NPTS + n] - m2;

    const float nx = fminf(fmaxf((x / d + 0.5f) * (float)RES, 0.0f), (float)(RES - 1));
    const float ny = fminf(fmaxf((y / d + 0.5f) * (float)RES, 0.0f), (float)(RES - 1));
    const float nz = fminf(fmaxf((z / d + 0.5f) * (float)RES, 0.0f), (float)(RES - 1));

    float* nb_ = norm_out + (size_t)b * 3 * NPTS;
    nb_[n]            = nx;
    nb_[NPTS + n]     = ny;
    nb_[2 * NPTS + n] = nz;

    const int ix = (int)rintf(nx);
    const int iy = (int)rintf(ny);
    const int iz = (int)rintf(nz);
    const int idx = (ix * RES + iy) * RES + iz;

    idx_arr[(size_t)b * NPTS + n] = idx;
    atomicAdd(&counts[b * NVOX + idx], 1);
}

// ---------------------------------------------------------------------------
// Kernel 4: per-batch exclusive scan of 32768 counts (1 block/batch)
// ---------------------------------------------------------------------------
__global__ __launch_bounds__(1024) void scan_kernel(const int* __restrict__ counts,
                                                    int* __restrict__ offsets,
                                                    int* __restrict__ cursor) {
    const int b = blockIdx.x;
    const int t = threadIdx.x;            // each owns 32 values
    const int base = b * NVOX + t * 32;
    int sum = 0;
#pragma unroll
    for (int i = 0; i < 32; ++i) sum += counts[base + i];

    const int lane = t & 63, wid = t >> 6;  // 16 waves
    int x = sum;
    for (int off = 1; off < 64; off <<= 1) {
        int y = __shfl_up(x, off, 64);
        if (lane >= off) x += y;
    }
    __shared__ int wsum[16];
    if (lane == 63) wsum[wid] = x;
    __syncthreads();
    if (t == 0) {
        int run = 0;
        for (int w = 0; w < 16; ++w) { int tmp = wsum[w]; wsum[w] = run; run += tmp; }
    }
    __syncthreads();
    int pre = x - sum + wsum[wid];
#pragma unroll
    for (int i = 0; i < 32; ++i) {
        offsets[base + i] = pre;
        cursor[base + i]  = pre;
        pre += counts[base + i];
    }
}

// ---------------------------------------------------------------------------
// Kernel 5: counting-sort placement.
//   fwd=1: perm[n]   = pos   (for permute_kernel scatter-write)
//   fwd=0: perm[pos] = n     (for fallback gather)
//   both:  vox16[pos] = voxel id
// ---------------------------------------------------------------------------
__global__ void place_kernel(const int* __restrict__ idx_arr,
                             int* __restrict__ cursor,
                             int* __restrict__ perm,
                             unsigned short* __restrict__ vox16,
                             int fwd) {
    const int n = blockIdx.x * blockDim.x + threadIdx.x;
    const int b = blockIdx.y;
    if (n >= NPTS) return;
    const int idx = idx_arr[(size_t)b * NPTS + n];
    const int pos = atomicAdd(&cursor[b * NVOX + idx], 1);
    vox16[(size_t)b * NPTS + pos] = (unsigned short)idx;
    if (fwd) perm[(size_t)b * NPTS + n]   = pos;
    else     perm[(size_t)b * NPTS + pos] = n;
}

// ---------------------------------------------------------------------------
// Kernel 6: permute features into sorted order: featS[pos][c] = feat[c][n]
//   Reads coalesced along n (LDS 64x64 tile), writes 256B contiguous rows.
// ---------------------------------------------------------------------------
__global__ void permute_kernel(const float* __restrict__ feat,
                               const int* __restrict__ perm,
                               float* __restrict__ featS, size_t bstride,
                               int b0) {
    __shared__ float tile[64][65];
    const int b  = b0 + blockIdx.y;
    const int n0 = blockIdx.x * 64;
    const int tx = threadIdx.x & 63;
    const int ty = threadIdx.x >> 6;      // 0..3 (block 256)
    const float* fb = feat + (size_t)b * NC * NPTS;
    if (n0 + tx < NPTS) {
#pragma unroll
        for (int c = ty; c < 64; c += 4)
            tile[c][tx] = fb[(size_t)c * NPTS + n0 + tx];
    }
    __syncthreads();
    float* fS = featS + (size_t)blockIdx.y * bstride;
    const int* pb = perm + (size_t)b * NPTS;
#pragma unroll
    for (int r = ty; r < 64; r += 4) {
        const int n = n0 + r;
        if (n < NPTS) {
            const int pos = pb[n];
            fS[(size_t)pos * NC + tx] = tile[tx][r];
        }
    }
}

// ---------------------------------------------------------------------------
// Kernel 7: gather — block = 64 consecutive voxels. Streaming reads of the
//   contiguous featS rows [start,end), LDS accumulate by voxel, fused divide.
//   use_fS=0 is the (slow) fallback reading feat directly via perm[pos]=n.
// ---------------------------------------------------------------------------
__global__ __launch_bounds__(512) void gather_kernel(
        const float* __restrict__ featS, size_t bstride,
        const float* __restrict__ feat, const int* __restrict__ perm,
        const unsigned short* __restrict__ vox16,
        const int* __restrict__ offsets, const int* __restrict__ counts,
        float* __restrict__ out, int b0, int use_fS) {
    __shared__ float tile[64 * 65];
    const int b    = b0 + blockIdx.y;
    const int v0   = blockIdx.x * 64;
    const int lane = threadIdx.x & 63;
    const int wid  = threadIdx.x >> 6;    // 0..7

    for (int i = threadIdx.x; i < 64 * 65; i += 512) tile[i] = 0.f;
    __syncthreads();

    const int start = offsets[b * NVOX + v0];
    const int end   = offsets[b * NVOX + v0 + 63] + counts[b * NVOX + v0 + 63];
    const unsigned short* vb = vox16 + (size_t)b * NPTS;

    int p = start + wid;
    if (use_fS) {
        const float* fS = featS + (size_t)blockIdx.y * bstride;
        for (; p + 24 < end; p += 32) {     // 4 points/wave/iter, 8 waves
            const int w0 = vb[p], w1 = vb[p + 8], w2 = vb[p + 16], w3 = vb[p + 24];
            const float f0 = fS[(size_t)p * NC + lane];
            const float f1 = fS[(size_t)(p + 8) * NC + lane];
            const float f2 = fS[(size_t)(p + 16) * NC + lane];
            const float f3 = fS[(size_t)(p + 24) * NC + lane];
            atomicAdd(&tile[(w0 - v0) * 65 + lane], f0);
            atomicAdd(&tile[(w1 - v0) * 65 + lane], f1);
            atomicAdd(&tile[(w2 - v0) * 65 + lane], f2);
            atomicAdd(&tile[(w3 - v0) * 65 + lane], f3);
        }
        for (; p < end; p += 8) {
            const int w = vb[p];
            const float f = fS[(size_t)p * NC + lane];
            atomicAdd(&tile[(w - v0) * 65 + lane], f);
        }
    } else {
        const float* fb = feat + (size_t)b * NC * NPTS + (size_t)lane * NPTS;
        const int* pm = perm + (size_t)b * NPTS;
        for (; p < end; p += 8) {
            const int w = vb[p];
            const float f = fb[pm[p]];
            atomicAdd(&tile[(w - v0) * 65 + lane], f);
        }
    }
    __syncthreads();

    const float cnt = fmaxf((float)counts[b * NVOX + v0 + lane], 1.f);
    float* ob = out + (size_t)b * NC * NVOX + v0 + lane;
#pragma unroll
    for (int c = wid; c < 64; c += 8)
        ob[(size_t)c * NVOX] = tile[lane * 65 + c] / cnt;
}

// ---------------------------------------------------------------------------
extern "C" void kernel_launch(void* const* d_in, const int* in_sizes, int n_in,
                              void* d_out, int out_size, void* d_ws, size_t ws_size,
                              hipStream_t stream) {
    const float* feat   = (const float*)d_in[0];  // [8,64,100000]
    const float* coords = (const float*)d_in[1];  // [8,3,100000]

    float* out      = (float*)d_out;                 // [8,64,32,32,32]
    float* norm_out = out + (size_t)NB * NC * NVOX;  // [8,3,100000]

    float*          ws_sum  = (float*)d_ws + SUM_OFF;
    unsigned int*   ws_rad  = (unsigned int*)d_ws + RAD_OFF;
    int*            counts  = (int*)d_ws + CNT_OFF;
    int*            offsets = (int*)d_ws + OFFS_OFF;
    int*            cursor  = (int*)d_ws + CURS_OFF;
    int*            idx_arr = (int*)d_ws + IDX_OFF;
    int*            perm    = (int*)d_ws + PERM_OFF;
    unsigned short* vox16   = (unsigned short*)((int*)d_ws + VOX_OFF);
    float*          featS   = (float*)d_ws + FS_OFF;

    const size_t need_all = ((size_t)FS_OFF + (size_t)NB * NPTS * NC) * 4;
    const size_t need_one = ((size_t)FS_OFF + (size_t)NPTS * NC) * 4;
    // mode 0: featS for all batches; 1: one batch at a time; 2: no featS
    const int mode = (ws_size >= need_all) ? 0 : (ws_size >= need_one ? 1 : 2);

    hipMemsetAsync(d_ws, 0, ((size_t)CNT_OFF + (size_t)NB * NVOX) * 4, stream);

    sum_kernel<<<dim3(32, NB), 256, 0, stream>>>(coords, ws_sum);
    rad_kernel<<<dim3(32, NB), 256, 0, stream>>>(coords, ws_sum, ws_rad);
    index_kernel<<<dim3((NPTS + 255) / 256, NB), 256, 0, stream>>>(
        coords, ws_sum, ws_rad, norm_out, idx_arr, counts);
    scan_kernel<<<dim3(NB), 1024, 0, stream>>>(counts, offsets, cursor);
    place_kernel<<<dim3((NPTS + 255) / 256, NB), 256, 0, stream>>>(
        idx_arr, cursor, perm, vox16, mode != 2);

    const int ntile = (NPTS + 63) / 64;
    if (mode == 0) {
        permute_kernel<<<dim3(ntile, NB), 256, 0, stream>>>(
            feat, perm, featS, (size_t)NPTS * NC, 0);
        gather_kernel<<<dim3(NVOX / 64, NB), 512, 0, stream>>>(
            featS, (size_t)NPTS * NC, feat, perm, vox16, offsets, counts, out, 0, 1);
    } else if (mode == 1) {
        for (int b = 0; b < NB; ++b) {
            permute_kernel<<<dim3(ntile, 1), 256, 0, stream>>>(
                feat, perm, featS, 0, b);
            gather_kernel<<<dim3(NVOX / 64, 1), 512, 0, stream>>>(
                featS, 0, feat, perm, vox16, offsets, counts, out, b, 1);
        }
    } else {
        gather_kernel<<<dim3(NVOX / 64, NB), 512, 0, stream>>>(
            featS, 0, feat, perm, vox16, offsets, counts, out, 0, 0);
    }
}

// Round 4
// 1827.448 us; speedup vs baseline: 1.0246x; 1.0246x over previous
//
#include <hip/hip_runtime.h>

#define RES   32
#define NVOX  (RES * RES * RES)   // 32768
#define NB    8
#define NC    64
#define NPTS  100000
#define NTILE ((NPTS + 255) / 256)   // 391

// workspace layout in 4-byte words
#define SUM_OFF  0                          // 24 floats
#define RAD_OFF  32                         // 8 uints
#define CNT_OFF  64                         // NB*NVOX ints        (1 MB)
#define OFF_OFF  (CNT_OFF + NB * NVOX)      // NB*NVOX ints        (1 MB)
#define IR_OFF   (OFF_OFF + NB * NVOX)      // NB*NPTS uints       (3.2 MB)  (idx<<16)|rank
#define VX_OFF   (IR_OFF  + NB * NPTS)      // NB*NPTS ushorts     (1.6 MB)
#define FS_OFF   (VX_OFF  + NB * NPTS / 2)  // featS bf16: NB*NPTS*CH*2 bytes

__device__ __forceinline__ unsigned short f2bf(float x) {
    unsigned u = __float_as_uint(x);
    return (unsigned short)((u + 0x7FFFu + ((u >> 16) & 1u)) >> 16);  // RNE
}
__device__ __forceinline__ float bf2f(unsigned short h) {
    return __uint_as_float((unsigned)h << 16);
}

// ---------------------------------------------------------------------------
// Kernel 1: per-batch sum of coords -> ws_sum[b*3+k]
// ---------------------------------------------------------------------------
__global__ void sum_kernel(const float* __restrict__ coords,
                           float* __restrict__ ws_sum) {
    const int b = blockIdx.y;
    const float* cb = coords + (size_t)b * 3 * NPTS;
    float s0 = 0.f, s1 = 0.f, s2 = 0.f;
    for (int n = blockIdx.x * blockDim.x + threadIdx.x; n < NPTS;
         n += blockDim.x * gridDim.x) {
        s0 += cb[n];
        s1 += cb[NPTS + n];
        s2 += cb[2 * NPTS + n];
    }
    for (int off = 32; off > 0; off >>= 1) {
        s0 += __shfl_down(s0, off, 64);
        s1 += __shfl_down(s1, off, 64);
        s2 += __shfl_down(s2, off, 64);
    }
    if ((threadIdx.x & 63) == 0) {
        atomicAdd(&ws_sum[b * 3 + 0], s0);
        atomicAdd(&ws_sum[b * 3 + 1], s1);
        atomicAdd(&ws_sum[b * 3 + 2], s2);
    }
}

// ---------------------------------------------------------------------------
// Kernel 2: per-batch max squared radius -> ws_rad[b] (uint bits, monotone)
// ---------------------------------------------------------------------------
__global__ void rad_kernel(const float* __restrict__ coords,
                           const float* __restrict__ ws_sum,
                           unsigned int* __restrict__ ws_rad) {
#pragma clang fp contract(off)
    const int b = blockIdx.y;
    const float* cb = coords + (size_t)b * 3 * NPTS;
    const float m0 = ws_sum[b * 3 + 0] / (float)NPTS;
    const float m1 = ws_sum[b * 3 + 1] / (float)NPTS;
    const float m2 = ws_sum[b * 3 + 2] / (float)NPTS;
    float mx = 0.f;
    for (int n = blockIdx.x * blockDim.x + threadIdx.x; n < NPTS;
         n += blockDim.x * gridDim.x) {
        float dx = cb[n] - m0;
        float dy = cb[NPTS + n] - m1;
        float dz = cb[2 * NPTS + n] - m2;
        float sq = dx * dx + dy * dy + dz * dz;
        mx = fmaxf(mx, sq);
    }
    for (int off = 32; off > 0; off >>= 1)
        mx = fmaxf(mx, __shfl_down(mx, off, 64));
    if ((threadIdx.x & 63) == 0)
        atomicMax(&ws_rad[b], __float_as_uint(mx));
}

// ---------------------------------------------------------------------------
// Kernel 3: per point: norm coords (output 1), voxel idx, histogram + rank.
//   The atomicAdd return value is the within-voxel rank -> pack (idx<<16)|rank.
// ---------------------------------------------------------------------------
__global__ void index_kernel(const float* __restrict__ coords,
                             const float* __restrict__ ws_sum,
                             const unsigned int* __restrict__ ws_rad,
                             float* __restrict__ norm_out,
                             unsigned int* __restrict__ idxrank,
                             int* __restrict__ counts) {
#pragma clang fp contract(off)
    const int n = blockIdx.x * blockDim.x + threadIdx.x;
    const int b = blockIdx.y;
    if (n >= NPTS) return;

    const float m0 = ws_sum[b * 3 + 0] / (float)NPTS;
    const float m1 = ws_sum[b * 3 + 1] / (float)NPTS;
    const float m2 = ws_sum[b * 3 + 2] / (float)NPTS;
    const float r  = sqrtf(__uint_as_float(ws_rad[b]));
    const float d  = r * 2.0f;   // EPS == 0

    const float* cb = coords + (size_t)b * 3 * NPTS;
    const float x = cb[n] - m0;
    const float y = cb[NPTS + n] - m1;
    const float z = cb[2 * NPTS + n] - m2;

    const float nx = fminf(fmaxf((x / d + 0.5f) * (float)RES, 0.0f), (float)(RES - 1));
    const float ny = fminf(fmaxf((y / d + 0.5f) * (float)RES, 0.0f), (float)(RES - 1));
    const float nz = fminf(fmaxf((z / d + 0.5f) * (float)RES, 0.0f), (float)(RES - 1));

    float* nb_ = norm_out + (size_t)b * 3 * NPTS;
    nb_[n]            = nx;
    nb_[NPTS + n]     = ny;
    nb_[2 * NPTS + n] = nz;

    const int ix = (int)rintf(nx);
    const int iy = (int)rintf(ny);
    const int iz = (int)rintf(nz);
    const int idx = (ix * RES + iy) * RES + iz;

    const int rank = atomicAdd(&counts[b * NVOX + idx], 1);
    idxrank[(size_t)b * NPTS + n] = ((unsigned)idx << 16) | (unsigned)(rank & 0xFFFF);
}

// ---------------------------------------------------------------------------
// Kernel 4: per-batch exclusive scan of 32768 counts -> offsets
// ---------------------------------------------------------------------------
__global__ __launch_bounds__(1024) void scan_kernel(const int* __restrict__ counts,
                                                    int* __restrict__ offsets) {
    const int b = blockIdx.x;
    const int t = threadIdx.x;            // each owns 32 values
    const int base = b * NVOX + t * 32;
    int sum = 0;
#pragma unroll
    for (int i = 0; i < 32; ++i) sum += counts[base + i];

    const int lane = t & 63, wid = t >> 6;  // 16 waves
    int x = sum;
    for (int off = 1; off < 64; off <<= 1) {
        int y = __shfl_up(x, off, 64);
        if (lane >= off) x += y;
    }
    __shared__ int wsum[16];
    if (lane == 63) wsum[wid] = x;
    __syncthreads();
    if (t == 0) {
        int run = 0;
        for (int w = 0; w < 16; ++w) { int tmp = wsum[w]; wsum[w] = run; run += tmp; }
    }
    __syncthreads();
    int pre = x - sum + wsum[wid];
#pragma unroll
    for (int i = 0; i < 32; ++i) {
        offsets[base + i] = pre;
        pre += counts[base + i];
    }
}

// ---------------------------------------------------------------------------
// Kernel 5: vox16[pos] = voxel id (pos = offsets[idx] + rank, deterministic)
// ---------------------------------------------------------------------------
__global__ void vox_kernel(const unsigned int* __restrict__ idxrank,
                           const int* __restrict__ offsets,
                           unsigned short* __restrict__ vox16) {
    const int n = blockIdx.x * 256 + threadIdx.x;
    const int b = blockIdx.y;
    if (n >= NPTS) return;
    const unsigned pk = idxrank[(size_t)b * NPTS + n];
    const int idx = (int)(pk >> 16);
    const int pos = offsets[b * NVOX + idx] + (int)(pk & 0xFFFFu);
    vox16[(size_t)b * NPTS + pos] = (unsigned short)idx;
}

// ---------------------------------------------------------------------------
// Kernel 6: permute channels [c0, c0+CH) into sorted order (bf16):
//   featS[pos][c] = bf16(feat[c0+c][n]).  Reads coalesced along n.
// ---------------------------------------------------------------------------
template <int CH>
__global__ __launch_bounds__(256) void permute_kernel(
        const float* __restrict__ feat,
        const unsigned int* __restrict__ idxrank,
        const int* __restrict__ offsets,
        unsigned short* __restrict__ fS, int c0) {
    __shared__ float tile[CH][257];
    __shared__ int posbuf[256];
    const int b  = blockIdx.y;
    const int n0 = blockIdx.x * 256;
    const int t  = threadIdx.x;
    const int n  = n0 + t;
    const float* fb = feat + (size_t)b * NC * NPTS + (size_t)c0 * NPTS;
    if (n < NPTS) {
        const unsigned pk = idxrank[(size_t)b * NPTS + n];
        posbuf[t] = offsets[b * NVOX + (int)(pk >> 16)] + (int)(pk & 0xFFFFu);
#pragma unroll
        for (int c = 0; c < CH; ++c)
            tile[c][t] = fb[(size_t)c * NPTS + n];
    }
    __syncthreads();
    ushort2* fS2 = (ushort2*)fS + (size_t)b * NPTS * (CH / 2);
    const int nmax = min(256, NPTS - n0);
    for (int j = t; j < nmax * (CH / 2); j += 256) {
        const int r  = j / (CH / 2);
        const int cp = j - r * (CH / 2);
        const int pos = posbuf[r];
        ushort2 v;
        v.x = f2bf(tile[2 * cp][r]);
        v.y = f2bf(tile[2 * cp + 1][r]);
        fS2[(size_t)pos * (CH / 2) + cp] = v;
    }
}

// ---------------------------------------------------------------------------
// Kernel 7: gather — block = 64 consecutive voxels, channels [c0,c0+CH).
//   featS rows for the tile are CONTIGUOUS [start,end): pure streaming reads.
// ---------------------------------------------------------------------------
template <int CH>
__global__ __launch_bounds__(512) void gather_kernel(
        const unsigned short* __restrict__ fS,
        const unsigned short* __restrict__ vox16,
        const int* __restrict__ offsets, const int* __restrict__ counts,
        float* __restrict__ out, int c0) {
    __shared__ float tile[64][CH + 1];
    const int b  = blockIdx.y;
    const int v0 = blockIdx.x * 64;
    const int t  = threadIdx.x;

    for (int i = t; i < 64 * (CH + 1); i += 512) ((float*)tile)[i] = 0.f;
    __syncthreads();

    const int start = offsets[b * NVOX + v0];
    const int end   = offsets[b * NVOX + v0 + 63] + counts[b * NVOX + v0 + 63];
    const unsigned short* vb = vox16 + (size_t)b * NPTS + start;
    const ushort2* fS2 = (const ushort2*)fS +
                         (size_t)b * NPTS * (CH / 2) + (size_t)start * (CH / 2);
    const int npairs = (end - start) * (CH / 2);

    int q = t;
    for (; q + 1536 < npairs; q += 2048) {
        const ushort2 d0 = fS2[q];
        const ushort2 d1 = fS2[q + 512];
        const ushort2 d2 = fS2[q + 1024];
        const ushort2 d3 = fS2[q + 1536];
        const int e0 = 2 * q, e1 = 2 * (q + 512), e2 = 2 * (q + 1024), e3 = 2 * (q + 1536);
        const int p0 = e0 / CH, p1 = e1 / CH, p2 = e2 / CH, p3 = e3 / CH;
        const int w0 = vb[p0] - v0, w1 = vb[p1] - v0, w2 = vb[p2] - v0, w3 = vb[p3] - v0;
        const int c0_ = e0 - p0 * CH, c1_ = e1 - p1 * CH, c2_ = e2 - p2 * CH, c3_ = e3 - p3 * CH;
        atomicAdd(&tile[w0][c0_],     bf2f(d0.x));
        atomicAdd(&tile[w0][c0_ + 1], bf2f(d0.y));
        atomicAdd(&tile[w1][c1_],     bf2f(d1.x));
        atomicAdd(&tile[w1][c1_ + 1], bf2f(d1.y));
        atomicAdd(&tile[w2][c2_],     bf2f(d2.x));
        atomicAdd(&tile[w2][c2_ + 1], bf2f(d2.y));
        atomicAdd(&tile[w3][c3_],     bf2f(d3.x));
        atomicAdd(&tile[w3][c3_ + 1], bf2f(d3.y));
    }
    for (; q < npairs; q += 512) {
        const ushort2 d = fS2[q];
        const int e = 2 * q;
        const int p = e / CH;
        const int w = vb[p] - v0;
        const int c = e - p * CH;
        atomicAdd(&tile[w][c],     bf2f(d.x));
        atomicAdd(&tile[w][c + 1], bf2f(d.y));
    }
    __syncthreads();

    for (int i = t; i < 64 * CH; i += 512) {
        const int v = i & 63, c = i >> 6;
        const float cnt = fmaxf((float)counts[b * NVOX + v0 + v], 1.f);
        out[(size_t)b * NC * NVOX + (size_t)(c0 + c) * NVOX + v0 + v] =
            tile[v][c] / cnt;
    }
}

// ---------------------------------------------------------------------------
// Fallback (tiny workspace): direct global-atomic scatter + divide (round-1)
// ---------------------------------------------------------------------------
__global__ void scatter_fb(const float* __restrict__ feat,
                           const unsigned int* __restrict__ idxrank,
                           float* __restrict__ out) {
    const int n = blockIdx.x * 256 + threadIdx.x;
    const int b = blockIdx.y;
    if (n >= NPTS) return;
    const int idx = (int)(idxrank[(size_t)b * NPTS + n] >> 16);
    const float* fb = feat + (size_t)b * NC * NPTS + n;
    float* ob = out + (size_t)b * NC * NVOX + idx;
#pragma unroll 4
    for (int c = 0; c < NC; ++c)
        atomicAdd(ob + (size_t)c * NVOX, fb[(size_t)c * NPTS]);
}

__global__ void div_fb(float* __restrict__ out, const int* __restrict__ counts) {
    const int t = blockIdx.x * blockDim.x + threadIdx.x;  // over NB*NVOX
    const int b = t >> 15;
    const int v = t & (NVOX - 1);
    const float cnt = fmaxf((float)counts[t], 1.f);
    float* ob = out + (size_t)b * NC * NVOX + v;
#pragma unroll 8
    for (int c = 0; c < NC; ++c)
        ob[(size_t)c * NVOX] /= cnt;
}

// ---------------------------------------------------------------------------
template <int CH>
static void run_passes(const float* feat, unsigned int* idxrank, int* offsets,
                       int* counts, unsigned short* vox16, unsigned short* fS,
                       float* out, hipStream_t stream) {
    for (int c0 = 0; c0 < NC; c0 += CH) {
        permute_kernel<CH><<<dim3(NTILE, NB), 256, 0, stream>>>(
            feat, idxrank, offsets, fS, c0);
        gather_kernel<CH><<<dim3(NVOX / 64, NB), 512, 0, stream>>>(
            fS, vox16, offsets, counts, out, c0);
    }
}

extern "C" void kernel_launch(void* const* d_in, const int* in_sizes, int n_in,
                              void* d_out, int out_size, void* d_ws, size_t ws_size,
                              hipStream_t stream) {
    const float* feat   = (const float*)d_in[0];  // [8,64,100000]
    const float* coords = (const float*)d_in[1];  // [8,3,100000]

    float* out      = (float*)d_out;                 // [8,64,32,32,32]
    float* norm_out = out + (size_t)NB * NC * NVOX;  // [8,3,100000]

    float*          ws_sum  = (float*)d_ws + SUM_OFF;
    unsigned int*   ws_rad  = (unsigned int*)d_ws + RAD_OFF;
    int*            counts  = (int*)d_ws + CNT_OFF;
    int*            offsets = (int*)d_ws + OFF_OFF;
    unsigned int*   idxrank = (unsigned int*)d_ws + IR_OFF;
    unsigned short* vox16   = (unsigned short*)((int*)d_ws + VX_OFF);
    unsigned short* fS      = (unsigned short*)((int*)d_ws + FS_OFF);

    // largest channel chunk that fits the workspace (bf16 featS)
    int CH = 0;
    for (int ch = 16; ch >= 2; ch >>= 1) {
        const size_t need = (size_t)FS_OFF * 4 + (size_t)NB * NPTS * ch * 2;
        if (ws_size >= need) { CH = ch; break; }
    }

    hipMemsetAsync(d_ws, 0, ((size_t)CNT_OFF + (size_t)NB * NVOX) * 4, stream);

    sum_kernel<<<dim3(32, NB), 256, 0, stream>>>(coords, ws_sum);
    rad_kernel<<<dim3(32, NB), 256, 0, stream>>>(coords, ws_sum, ws_rad);
    index_kernel<<<dim3(NTILE, NB), 256, 0, stream>>>(
        coords, ws_sum, ws_rad, norm_out, idxrank, counts);

    if (CH == 0) {
        // tiny-workspace fallback: direct atomic scatter
        hipMemsetAsync(d_out, 0, (size_t)NB * NC * NVOX * 4, stream);
        scatter_fb<<<dim3(NTILE, NB), 256, 0, stream>>>(feat, idxrank, out);
        div_fb<<<dim3(NB * NVOX / 256), 256, 0, stream>>>(out, counts);
        return;
    }

    scan_kernel<<<dim3(NB), 1024, 0, stream>>>(counts, offsets);
    vox_kernel<<<dim3(NTILE, NB), 256, 0, stream>>>(idxrank, offsets, vox16);

    switch (CH) {
        case 16: run_passes<16>(feat, idxrank, offsets, counts, vox16, fS, out, stream); break;
        case 8:  run_passes<8>(feat, idxrank, offsets, counts, vox16, fS, out, stream); break;
        case 4:  run_passes<4>(feat, idxrank, offsets, counts, vox16, fS, out, stream); break;
        default: run_passes<2>(feat, idxrank, offsets, counts, vox16, fS, out, stream); break;
    }
}

// Round 5
// 729.126 us; speedup vs baseline: 2.5681x; 2.5064x over previous
//
#include <hip/hip_runtime.h>

#define RES   32
#define NVOX  (RES * RES * RES)   // 32768
#define NB    8
#define NC    64
#define NPTS  100000
#define NTILE ((NPTS + 255) / 256)   // 391

// workspace layout in 4-byte words
#define SUM_OFF  0                          // 24 floats
#define RAD_OFF  32                         // 8 uints
#define CNT_OFF  64                         // NB*NVOX ints        (1 MB)
#define OFF_OFF  (CNT_OFF + NB * NVOX)      // NB*NVOX ints        (1 MB)
#define IR_OFF   (OFF_OFF + NB * NVOX)      // NB*NPTS uints       (3.2 MB)  (idx<<16)|rank
#define FS_OFF   (IR_OFF  + NB * NPTS)      // featS bf16: NB*NPTS*CH*2 bytes

__device__ __forceinline__ unsigned short f2bf(float x) {
    unsigned u = __float_as_uint(x);
    return (unsigned short)((u + 0x7FFFu + ((u >> 16) & 1u)) >> 16);  // RNE
}
__device__ __forceinline__ float bf2f(unsigned short h) {
    return __uint_as_float((unsigned)h << 16);
}

// ---------------------------------------------------------------------------
// Kernel 1: per-batch sum of coords -> ws_sum[b*3+k]
// ---------------------------------------------------------------------------
__global__ void sum_kernel(const float* __restrict__ coords,
                           float* __restrict__ ws_sum) {
    const int b = blockIdx.y;
    const float* cb = coords + (size_t)b * 3 * NPTS;
    float s0 = 0.f, s1 = 0.f, s2 = 0.f;
    for (int n = blockIdx.x * blockDim.x + threadIdx.x; n < NPTS;
         n += blockDim.x * gridDim.x) {
        s0 += cb[n];
        s1 += cb[NPTS + n];
        s2 += cb[2 * NPTS + n];
    }
    for (int off = 32; off > 0; off >>= 1) {
        s0 += __shfl_down(s0, off, 64);
        s1 += __shfl_down(s1, off, 64);
        s2 += __shfl_down(s2, off, 64);
    }
    if ((threadIdx.x & 63) == 0) {
        atomicAdd(&ws_sum[b * 3 + 0], s0);
        atomicAdd(&ws_sum[b * 3 + 1], s1);
        atomicAdd(&ws_sum[b * 3 + 2], s2);
    }
}

// ---------------------------------------------------------------------------
// Kernel 2: per-batch max squared radius -> ws_rad[b] (uint bits, monotone)
// ---------------------------------------------------------------------------
__global__ void rad_kernel(const float* __restrict__ coords,
                           const float* __restrict__ ws_sum,
                           unsigned int* __restrict__ ws_rad) {
#pragma clang fp contract(off)
    const int b = blockIdx.y;
    const float* cb = coords + (size_t)b * 3 * NPTS;
    const float m0 = ws_sum[b * 3 + 0] / (float)NPTS;
    const float m1 = ws_sum[b * 3 + 1] / (float)NPTS;
    const float m2 = ws_sum[b * 3 + 2] / (float)NPTS;
    float mx = 0.f;
    for (int n = blockIdx.x * blockDim.x + threadIdx.x; n < NPTS;
         n += blockDim.x * gridDim.x) {
        float dx = cb[n] - m0;
        float dy = cb[NPTS + n] - m1;
        float dz = cb[2 * NPTS + n] - m2;
        float sq = dx * dx + dy * dy + dz * dz;
        mx = fmaxf(mx, sq);
    }
    for (int off = 32; off > 0; off >>= 1)
        mx = fmaxf(mx, __shfl_down(mx, off, 64));
    if ((threadIdx.x & 63) == 0)
        atomicMax(&ws_rad[b], __float_as_uint(mx));
}

// ---------------------------------------------------------------------------
// Kernel 3: per point: norm coords (output 1), voxel idx, histogram + rank.
// ---------------------------------------------------------------------------
__global__ void index_kernel(const float* __restrict__ coords,
                             const float* __restrict__ ws_sum,
                             const unsigned int* __restrict__ ws_rad,
                             float* __restrict__ norm_out,
                             unsigned int* __restrict__ idxrank,
                             int* __restrict__ counts) {
#pragma clang fp contract(off)
    const int n = blockIdx.x * blockDim.x + threadIdx.x;
    const int b = blockIdx.y;
    if (n >= NPTS) return;

    const float m0 = ws_sum[b * 3 + 0] / (float)NPTS;
    const float m1 = ws_sum[b * 3 + 1] / (float)NPTS;
    const float m2 = ws_sum[b * 3 + 2] / (float)NPTS;
    const float r  = sqrtf(__uint_as_float(ws_rad[b]));
    const float d  = r * 2.0f;   // EPS == 0

    const float* cb = coords + (size_t)b * 3 * NPTS;
    const float x = cb[n] - m0;
    const float y = cb[NPTS + n] - m1;
    const float z = cb[2 * NPTS + n] - m2;

    const float nx = fminf(fmaxf((x / d + 0.5f) * (float)RES, 0.0f), (float)(RES - 1));
    const float ny = fminf(fmaxf((y / d + 0.5f) * (float)RES, 0.0f), (float)(RES - 1));
    const float nz = fminf(fmaxf((z / d + 0.5f) * (float)RES, 0.0f), (float)(RES - 1));

    float* nb_ = norm_out + (size_t)b * 3 * NPTS;
    nb_[n]            = nx;
    nb_[NPTS + n]     = ny;
    nb_[2 * NPTS + n] = nz;

    const int ix = (int)rintf(nx);
    const int iy = (int)rintf(ny);
    const int iz = (int)rintf(nz);
    const int idx = (ix * RES + iy) * RES + iz;

    const int rank = atomicAdd(&counts[b * NVOX + idx], 1);
    idxrank[(size_t)b * NPTS + n] = ((unsigned)idx << 16) | (unsigned)(rank & 0xFFFF);
}

// ---------------------------------------------------------------------------
// Kernel 4: per-batch exclusive scan of 32768 counts -> offsets
// ---------------------------------------------------------------------------
__global__ __launch_bounds__(1024) void scan_kernel(const int* __restrict__ counts,
                                                    int* __restrict__ offsets) {
    const int b = blockIdx.x;
    const int t = threadIdx.x;            // each owns 32 values
    const int base = b * NVOX + t * 32;
    int sum = 0;
#pragma unroll
    for (int i = 0; i < 32; ++i) sum += counts[base + i];

    const int lane = t & 63, wid = t >> 6;  // 16 waves
    int x = sum;
    for (int off = 1; off < 64; off <<= 1) {
        int y = __shfl_up(x, off, 64);
        if (lane >= off) x += y;
    }
    __shared__ int wsum[16];
    if (lane == 63) wsum[wid] = x;
    __syncthreads();
    if (t == 0) {
        int run = 0;
        for (int w = 0; w < 16; ++w) { int tmp = wsum[w]; wsum[w] = run; run += tmp; }
    }
    __syncthreads();
    int pre = x - sum + wsum[wid];
#pragma unroll
    for (int i = 0; i < 32; ++i) {
        offsets[base + i] = pre;
        pre += counts[base + i];
    }
}

// ---------------------------------------------------------------------------
// Kernel 5: permute channels [c0, c0+CH) into sorted order (bf16):
//   featS[pos][c] = bf16(feat[c0+c][n]).  Reads coalesced along n.
// ---------------------------------------------------------------------------
template <int CH>
__global__ __launch_bounds__(256) void permute_kernel(
        const float* __restrict__ feat,
        const unsigned int* __restrict__ idxrank,
        const int* __restrict__ offsets,
        unsigned short* __restrict__ fS, int c0) {
    __shared__ float tile[CH][257];
    __shared__ int posbuf[256];
    const int b  = blockIdx.y;
    const int n0 = blockIdx.x * 256;
    const int t  = threadIdx.x;
    const int n  = n0 + t;
    const float* fb = feat + (size_t)b * NC * NPTS + (size_t)c0 * NPTS;
    if (n < NPTS) {
        const unsigned pk = idxrank[(size_t)b * NPTS + n];
        posbuf[t] = offsets[b * NVOX + (int)(pk >> 16)] + (int)(pk & 0xFFFFu);
#pragma unroll
        for (int c = 0; c < CH; ++c)
            tile[c][t] = fb[(size_t)c * NPTS + n];
    }
    __syncthreads();
    ushort2* fS2 = (ushort2*)fS + (size_t)b * NPTS * (CH / 2);
    const int nmax = min(256, NPTS - n0);
    for (int j = t; j < nmax * (CH / 2); j += 256) {
        const int r  = j / (CH / 2);
        const int cp = j - r * (CH / 2);
        const int pos = posbuf[r];
        ushort2 v;
        v.x = f2bf(tile[2 * cp][r]);
        v.y = f2bf(tile[2 * cp + 1][r]);
        fS2[(size_t)pos * (CH / 2) + cp] = v;
    }
}

// ---------------------------------------------------------------------------
// Kernel 6: gather — NO ATOMICS. Block = 64 voxels; wave w owns voxels
//   [v0+8w, v0+8w+8): register accumulation over the voxel's contiguous
//   featS rows (8 points/instr), shfl-butterfly over point-slots, plain
//   ds_write of the finished row, coalesced transposed output.
// ---------------------------------------------------------------------------
template <int CH>
__global__ __launch_bounds__(512) void gather_kernel(
        const unsigned short* __restrict__ fS,
        const int* __restrict__ offsets, const int* __restrict__ counts,
        float* __restrict__ out, int c0) {
    constexpr int HP  = CH / 2;       // ushort2 pairs per point
    constexpr int PPW = 64 / HP;      // points per wave-instruction
    __shared__ float tile[64][CH + 2];   // +2 keeps rows float2-aligned
    const int b    = blockIdx.y;
    const int v0   = blockIdx.x * 64;
    const int t    = threadIdx.x;
    const int wid  = t >> 6;          // 0..7
    const int lane = t & 63;
    const int pr   = lane % HP;       // pair-channel within point
    const int ps   = lane / HP;       // point slot

    // preload all 64 (offset,count) once per wave; distribute via shfl
    const int svL  = offsets[b * NVOX + v0 + lane];
    const int cntL = counts[b * NVOX + v0 + lane];

    const ushort2* fS2 = (const ushort2*)fS + (size_t)b * NPTS * HP;

#pragma unroll
    for (int k = 0; k < 8; ++k) {
        const int vsel = wid * 8 + k;
        const int s    = __shfl(svL, vsel, 64);
        const int cnt  = __shfl(cntL, vsel, 64);
        float ax = 0.f, ay = 0.f;
        const int e = s + cnt;
        for (int p = s + ps; p < e; p += PPW) {
            const ushort2 d = fS2[(size_t)p * HP + pr];
            ax += bf2f(d.x);
            ay += bf2f(d.y);
        }
        // reduce over the point-slot dimension (lanes differing above bit log2(HP))
        for (int m = HP; m < 64; m <<= 1) {
            ax += __shfl_xor(ax, m, 64);
            ay += __shfl_xor(ay, m, 64);
        }
        if (ps == 0) {
            const float cf = fmaxf((float)cnt, 1.f);
            *(float2*)&tile[vsel][2 * pr] = make_float2(ax / cf, ay / cf);
        }
    }
    __syncthreads();

#pragma unroll
    for (int i = t; i < 64 * CH; i += 512) {
        const int v = i & 63, c = i >> 6;
        out[(size_t)b * NC * NVOX + (size_t)(c0 + c) * NVOX + v0 + v] = tile[v][c];
    }
}

// ---------------------------------------------------------------------------
// Fallback (tiny workspace): direct global-atomic scatter + divide
// ---------------------------------------------------------------------------
__global__ void scatter_fb(const float* __restrict__ feat,
                           const unsigned int* __restrict__ idxrank,
                           float* __restrict__ out) {
    const int n = blockIdx.x * 256 + threadIdx.x;
    const int b = blockIdx.y;
    if (n >= NPTS) return;
    const int idx = (int)(idxrank[(size_t)b * NPTS + n] >> 16);
    const float* fb = feat + (size_t)b * NC * NPTS + n;
    float* ob = out + (size_t)b * NC * NVOX + idx;
#pragma unroll 4
    for (int c = 0; c < NC; ++c)
        atomicAdd(ob + (size_t)c * NVOX, fb[(size_t)c * NPTS]);
}

__global__ void div_fb(float* __restrict__ out, const int* __restrict__ counts) {
    const int t = blockIdx.x * blockDim.x + threadIdx.x;  // over NB*NVOX
    const int b = t >> 15;
    const int v = t & (NVOX - 1);
    const float cnt = fmaxf((float)counts[t], 1.f);
    float* ob = out + (size_t)b * NC * NVOX + v;
#pragma unroll 8
    for (int c = 0; c < NC; ++c)
        ob[(size_t)c * NVOX] /= cnt;
}

// ---------------------------------------------------------------------------
template <int CH>
static void run_passes(const float* feat, unsigned int* idxrank, int* offsets,
                       int* counts, unsigned short* fS, float* out,
                       hipStream_t stream) {
    for (int c0 = 0; c0 < NC; c0 += CH) {
        permute_kernel<CH><<<dim3(NTILE, NB), 256, 0, stream>>>(
            feat, idxrank, offsets, fS, c0);
        gather_kernel<CH><<<dim3(NVOX / 64, NB), 512, 0, stream>>>(
            fS, offsets, counts, out, c0);
    }
}

extern "C" void kernel_launch(void* const* d_in, const int* in_sizes, int n_in,
                              void* d_out, int out_size, void* d_ws, size_t ws_size,
                              hipStream_t stream) {
    const float* feat   = (const float*)d_in[0];  // [8,64,100000]
    const float* coords = (const float*)d_in[1];  // [8,3,100000]

    float* out      = (float*)d_out;                 // [8,64,32,32,32]
    float* norm_out = out + (size_t)NB * NC * NVOX;  // [8,3,100000]

    float*          ws_sum  = (float*)d_ws + SUM_OFF;
    unsigned int*   ws_rad  = (unsigned int*)d_ws + RAD_OFF;
    int*            counts  = (int*)d_ws + CNT_OFF;
    int*            offsets = (int*)d_ws + OFF_OFF;
    unsigned int*   idxrank = (unsigned int*)d_ws + IR_OFF;
    unsigned short* fS      = (unsigned short*)((int*)d_ws + FS_OFF);

    // largest channel chunk that fits the workspace (bf16 featS)
    int CH = 0;
    for (int ch = 16; ch >= 2; ch >>= 1) {
        const size_t need = (size_t)FS_OFF * 4 + (size_t)NB * NPTS * ch * 2;
        if (ws_size >= need) { CH = ch; break; }
    }

    hipMemsetAsync(d_ws, 0, ((size_t)CNT_OFF + (size_t)NB * NVOX) * 4, stream);

    sum_kernel<<<dim3(32, NB), 256, 0, stream>>>(coords, ws_sum);
    rad_kernel<<<dim3(32, NB), 256, 0, stream>>>(coords, ws_sum, ws_rad);
    index_kernel<<<dim3(NTILE, NB), 256, 0, stream>>>(
        coords, ws_sum, ws_rad, norm_out, idxrank, counts);

    if (CH == 0) {
        hipMemsetAsync(d_out, 0, (size_t)NB * NC * NVOX * 4, stream);
        scatter_fb<<<dim3(NTILE, NB), 256, 0, stream>>>(feat, idxrank, out);
        div_fb<<<dim3(NB * NVOX / 256), 256, 0, stream>>>(out, counts);
        return;
    }

    scan_kernel<<<dim3(NB), 1024, 0, stream>>>(counts, offsets);

    switch (CH) {
        case 16: run_passes<16>(feat, idxrank, offsets, counts, fS, out, stream); break;
        case 8:  run_passes<8>(feat, idxrank, offsets, counts, fS, out, stream); break;
        case 4:  run_passes<4>(feat, idxrank, offsets, counts, fS, out, stream); break;
        default: run_passes<2>(feat, idxrank, offsets, counts, fS, out, stream); break;
    }
}

// Round 6
// 585.623 us; speedup vs baseline: 3.1973x; 1.2450x over previous
//
#include <hip/hip_runtime.h>

#define RES   32
#define NVOX  (RES * RES * RES)   // 32768
#define NB    8
#define NC    64
#define NPTS  100000
#define NTILE   ((NPTS + 255) / 256)  // 391
#define NTILE64 ((NPTS + 63) / 64)    // 1563

// workspace layout in 4-byte words
#define SUM_OFF  0                          // 24 floats
#define RAD_OFF  32                         // 8 uints
#define CNT_OFF  64                         // NB*NVOX ints        (1 MB)
#define OFF_OFF  (CNT_OFF + NB * NVOX)      // NB*NVOX ints        (1 MB)
#define IR_OFF   (OFF_OFF + NB * NVOX)      // NB*NPTS uints       (3.2 MB)  (idx<<16)|rank
#define FS_OFF   (IR_OFF  + NB * NPTS)      // featS bf16: NB*NPTS*CH*2 bytes

__device__ __forceinline__ unsigned short f2bf(float x) {
    unsigned u = __float_as_uint(x);
    return (unsigned short)((u + 0x7FFFu + ((u >> 16) & 1u)) >> 16);  // RNE
}
__device__ __forceinline__ float bf2f(unsigned short h) {
    return __uint_as_float((unsigned)h << 16);
}

// ---------------------------------------------------------------------------
// Kernel 1: per-batch sum of coords -> ws_sum[b*3+k]
// ---------------------------------------------------------------------------
__global__ void sum_kernel(const float* __restrict__ coords,
                           float* __restrict__ ws_sum) {
    const int b = blockIdx.y;
    const float* cb = coords + (size_t)b * 3 * NPTS;
    float s0 = 0.f, s1 = 0.f, s2 = 0.f;
    for (int n = blockIdx.x * blockDim.x + threadIdx.x; n < NPTS;
         n += blockDim.x * gridDim.x) {
        s0 += cb[n];
        s1 += cb[NPTS + n];
        s2 += cb[2 * NPTS + n];
    }
    for (int off = 32; off > 0; off >>= 1) {
        s0 += __shfl_down(s0, off, 64);
        s1 += __shfl_down(s1, off, 64);
        s2 += __shfl_down(s2, off, 64);
    }
    if ((threadIdx.x & 63) == 0) {
        atomicAdd(&ws_sum[b * 3 + 0], s0);
        atomicAdd(&ws_sum[b * 3 + 1], s1);
        atomicAdd(&ws_sum[b * 3 + 2], s2);
    }
}

// ---------------------------------------------------------------------------
// Kernel 2: per-batch max squared radius -> ws_rad[b] (uint bits, monotone)
// ---------------------------------------------------------------------------
__global__ void rad_kernel(const float* __restrict__ coords,
                           const float* __restrict__ ws_sum,
                           unsigned int* __restrict__ ws_rad) {
#pragma clang fp contract(off)
    const int b = blockIdx.y;
    const float* cb = coords + (size_t)b * 3 * NPTS;
    const float m0 = ws_sum[b * 3 + 0] / (float)NPTS;
    const float m1 = ws_sum[b * 3 + 1] / (float)NPTS;
    const float m2 = ws_sum[b * 3 + 2] / (float)NPTS;
    float mx = 0.f;
    for (int n = blockIdx.x * blockDim.x + threadIdx.x; n < NPTS;
         n += blockDim.x * gridDim.x) {
        float dx = cb[n] - m0;
        float dy = cb[NPTS + n] - m1;
        float dz = cb[2 * NPTS + n] - m2;
        float sq = dx * dx + dy * dy + dz * dz;
        mx = fmaxf(mx, sq);
    }
    for (int off = 32; off > 0; off >>= 1)
        mx = fmaxf(mx, __shfl_down(mx, off, 64));
    if ((threadIdx.x & 63) == 0)
        atomicMax(&ws_rad[b], __float_as_uint(mx));
}

// ---------------------------------------------------------------------------
// Kernel 3: per point: norm coords (output 1), voxel idx, histogram + rank.
// ---------------------------------------------------------------------------
__global__ void index_kernel(const float* __restrict__ coords,
                             const float* __restrict__ ws_sum,
                             const unsigned int* __restrict__ ws_rad,
                             float* __restrict__ norm_out,
                             unsigned int* __restrict__ idxrank,
                             int* __restrict__ counts) {
#pragma clang fp contract(off)
    const int n = blockIdx.x * blockDim.x + threadIdx.x;
    const int b = blockIdx.y;
    if (n >= NPTS) return;

    const float m0 = ws_sum[b * 3 + 0] / (float)NPTS;
    const float m1 = ws_sum[b * 3 + 1] / (float)NPTS;
    const float m2 = ws_sum[b * 3 + 2] / (float)NPTS;
    const float r  = sqrtf(__uint_as_float(ws_rad[b]));
    const float d  = r * 2.0f;   // EPS == 0

    const float* cb = coords + (size_t)b * 3 * NPTS;
    const float x = cb[n] - m0;
    const float y = cb[NPTS + n] - m1;
    const float z = cb[2 * NPTS + n] - m2;

    const float nx = fminf(fmaxf((x / d + 0.5f) * (float)RES, 0.0f), (float)(RES - 1));
    const float ny = fminf(fmaxf((y / d + 0.5f) * (float)RES, 0.0f), (float)(RES - 1));
    const float nz = fminf(fmaxf((z / d + 0.5f) * (float)RES, 0.0f), (float)(RES - 1));

    float* nb_ = norm_out + (size_t)b * 3 * NPTS;
    nb_[n]            = nx;
    nb_[NPTS + n]     = ny;
    nb_[2 * NPTS + n] = nz;

    const int ix = (int)rintf(nx);
    const int iy = (int)rintf(ny);
    const int iz = (int)rintf(nz);
    const int idx = (ix * RES + iy) * RES + iz;

    const int rank = atomicAdd(&counts[b * NVOX + idx], 1);
    idxrank[(size_t)b * NPTS + n] = ((unsigned)idx << 16) | (unsigned)(rank & 0xFFFF);
}

// ---------------------------------------------------------------------------
// Kernel 4: per-batch exclusive scan of 32768 counts -> offsets
// ---------------------------------------------------------------------------
__global__ __launch_bounds__(1024) void scan_kernel(const int* __restrict__ counts,
                                                    int* __restrict__ offsets) {
    const int b = blockIdx.x;
    const int t = threadIdx.x;            // each owns 32 values
    const int base = b * NVOX + t * 32;
    int sum = 0;
#pragma unroll
    for (int i = 0; i < 32; ++i) sum += counts[base + i];

    const int lane = t & 63, wid = t >> 6;  // 16 waves
    int x = sum;
    for (int off = 1; off < 64; off <<= 1) {
        int y = __shfl_up(x, off, 64);
        if (lane >= off) x += y;
    }
    __shared__ int wsum[16];
    if (lane == 63) wsum[wid] = x;
    __syncthreads();
    if (t == 0) {
        int run = 0;
        for (int w = 0; w < 16; ++w) { int tmp = wsum[w]; wsum[w] = run; run += tmp; }
    }
    __syncthreads();
    int pre = x - sum + wsum[wid];
#pragma unroll
    for (int i = 0; i < 32; ++i) {
        offsets[base + i] = pre;
        pre += counts[base + i];
    }
}

// ---------------------------------------------------------------------------
// Kernel 5 (single-pass): permute ALL 64 channels into sorted order (bf16).
//   Block: 64 points x 64 channels via fp32 LDS tile; reads coalesced along
//   n; writes each point's 128B row with 16 consecutive lanes (ushort4).
// ---------------------------------------------------------------------------
__global__ __launch_bounds__(256) void permute64_kernel(
        const float* __restrict__ feat,
        const unsigned int* __restrict__ idxrank,
        const int* __restrict__ offsets,
        unsigned short* __restrict__ fS) {
    __shared__ float tile[64][65];
    __shared__ int posbuf[64];
    const int b  = blockIdx.y;
    const int n0 = blockIdx.x * 64;
    const int t  = threadIdx.x;
    const int tx = t & 63, ty = t >> 6;   // ty 0..3
    const int n  = n0 + tx;
    const float* fb = feat + (size_t)b * NC * NPTS;
    if (n < NPTS) {
#pragma unroll
        for (int c = ty; c < 64; c += 4)
            tile[c][tx] = fb[(size_t)c * NPTS + n];
        if (ty == 0) {
            const unsigned pk = idxrank[(size_t)b * NPTS + n];
            posbuf[tx] = offsets[b * NVOX + (int)(pk >> 16)] + (int)(pk & 0xFFFFu);
        }
    }
    __syncthreads();
    ushort4* fS4 = (ushort4*)fS + (size_t)b * NPTS * 16;
    const int nmax = min(64, NPTS - n0);
    for (int j = t; j < nmax * 16; j += 256) {
        const int r = j >> 4, q = j & 15;     // point r, chunk q (4 channels)
        const int pos = posbuf[r];
        ushort4 v;
        v.x = f2bf(tile[4 * q][r]);
        v.y = f2bf(tile[4 * q + 1][r]);
        v.z = f2bf(tile[4 * q + 2][r]);
        v.w = f2bf(tile[4 * q + 3][r]);
        fS4[(size_t)pos * 16 + q] = v;
    }
}

// ---------------------------------------------------------------------------
// Kernel 6 (single-pass): gather all 64 channels, NO atomics.
//   Wave owns 8 voxels; lane = (point-slot ps 0..3, chunk q 0..15);
//   512B contiguous wave-loads, register accumulate, 2-step shfl butterfly,
//   float4 LDS write, fused divide, coalesced transposed output.
// ---------------------------------------------------------------------------
__global__ __launch_bounds__(512) void gather64_kernel(
        const unsigned short* __restrict__ fS,
        const int* __restrict__ offsets, const int* __restrict__ counts,
        float* __restrict__ out) {
    __shared__ float tile[64][68];   // row = 272B, 16B-aligned for float4
    const int b    = blockIdx.y;
    const int v0   = blockIdx.x * 64;
    const int t    = threadIdx.x;
    const int wid  = t >> 6;          // 0..7
    const int lane = t & 63;
    const int q    = lane & 15;       // channel chunk
    const int ps   = lane >> 4;       // point slot 0..3

    const int svL  = offsets[b * NVOX + v0 + lane];
    const int cntL = counts[b * NVOX + v0 + lane];
    const ushort4* fS4 = (const ushort4*)fS + (size_t)b * NPTS * 16;

#pragma unroll
    for (int k = 0; k < 8; ++k) {
        const int vsel = wid * 8 + k;
        const int s    = __shfl(svL, vsel, 64);
        const int cnt  = __shfl(cntL, vsel, 64);
        float a0 = 0.f, a1 = 0.f, a2 = 0.f, a3 = 0.f;
        const int e = s + cnt;
        for (int p = s + ps; p < e; p += 4) {
            const ushort4 d = fS4[(size_t)p * 16 + q];
            a0 += bf2f(d.x);
            a1 += bf2f(d.y);
            a2 += bf2f(d.z);
            a3 += bf2f(d.w);
        }
        for (int m = 16; m < 64; m <<= 1) {
            a0 += __shfl_xor(a0, m, 64);
            a1 += __shfl_xor(a1, m, 64);
            a2 += __shfl_xor(a2, m, 64);
            a3 += __shfl_xor(a3, m, 64);
        }
        if (ps == 0) {
            const float cf = fmaxf((float)cnt, 1.f);
            *(float4*)&tile[vsel][4 * q] =
                make_float4(a0 / cf, a1 / cf, a2 / cf, a3 / cf);
        }
    }
    __syncthreads();

#pragma unroll
    for (int i = t; i < 64 * NC; i += 512) {
        const int v = i & 63, c = i >> 6;
        out[(size_t)b * NC * NVOX + (size_t)c * NVOX + v0 + v] = tile[v][c];
    }
}

// ---------------------------------------------------------------------------
// Multi-pass kernels (smaller-workspace fallback, CH in {16,8,4,2})
// ---------------------------------------------------------------------------
template <int CH>
__global__ __launch_bounds__(256) void permute_kernel(
        const float* __restrict__ feat,
        const unsigned int* __restrict__ idxrank,
        const int* __restrict__ offsets,
        unsigned short* __restrict__ fS, int c0) {
    __shared__ float tile[CH][257];
    __shared__ int posbuf[256];
    const int b  = blockIdx.y;
    const int n0 = blockIdx.x * 256;
    const int t  = threadIdx.x;
    const int n  = n0 + t;
    const float* fb = feat + (size_t)b * NC * NPTS + (size_t)c0 * NPTS;
    if (n < NPTS) {
        const unsigned pk = idxrank[(size_t)b * NPTS + n];
        posbuf[t] = offsets[b * NVOX + (int)(pk >> 16)] + (int)(pk & 0xFFFFu);
#pragma unroll
        for (int c = 0; c < CH; ++c)
            tile[c][t] = fb[(size_t)c * NPTS + n];
    }
    __syncthreads();
    ushort2* fS2 = (ushort2*)fS + (size_t)b * NPTS * (CH / 2);
    const int nmax = min(256, NPTS - n0);
    for (int j = t; j < nmax * (CH / 2); j += 256) {
        const int r  = j / (CH / 2);
        const int cp = j - r * (CH / 2);
        const int pos = posbuf[r];
        ushort2 v;
        v.x = f2bf(tile[2 * cp][r]);
        v.y = f2bf(tile[2 * cp + 1][r]);
        fS2[(size_t)pos * (CH / 2) + cp] = v;
    }
}

template <int CH>
__global__ __launch_bounds__(512) void gather_kernel(
        const unsigned short* __restrict__ fS,
        const int* __restrict__ offsets, const int* __restrict__ counts,
        float* __restrict__ out, int c0) {
    constexpr int HP  = CH / 2;
    constexpr int PPW = 64 / HP;
    __shared__ float tile[64][CH + 2];
    const int b    = blockIdx.y;
    const int v0   = blockIdx.x * 64;
    const int t    = threadIdx.x;
    const int wid  = t >> 6;
    const int lane = t & 63;
    const int pr   = lane % HP;
    const int ps   = lane / HP;

    const int svL  = offsets[b * NVOX + v0 + lane];
    const int cntL = counts[b * NVOX + v0 + lane];
    const ushort2* fS2 = (const ushort2*)fS + (size_t)b * NPTS * HP;

#pragma unroll
    for (int k = 0; k < 8; ++k) {
        const int vsel = wid * 8 + k;
        const int s    = __shfl(svL, vsel, 64);
        const int cnt  = __shfl(cntL, vsel, 64);
        float ax = 0.f, ay = 0.f;
        const int e = s + cnt;
        for (int p = s + ps; p < e; p += PPW) {
            const ushort2 d = fS2[(size_t)p * HP + pr];
            ax += bf2f(d.x);
            ay += bf2f(d.y);
        }
        for (int m = HP; m < 64; m <<= 1) {
            ax += __shfl_xor(ax, m, 64);
            ay += __shfl_xor(ay, m, 64);
        }
        if (ps == 0) {
            const float cf = fmaxf((float)cnt, 1.f);
            *(float2*)&tile[vsel][2 * pr] = make_float2(ax / cf, ay / cf);
        }
    }
    __syncthreads();

#pragma unroll
    for (int i = t; i < 64 * CH; i += 512) {
        const int v = i & 63, c = i >> 6;
        out[(size_t)b * NC * NVOX + (size_t)(c0 + c) * NVOX + v0 + v] = tile[v][c];
    }
}

// ---------------------------------------------------------------------------
// Tiny-workspace fallback: direct global-atomic scatter + divide
// ---------------------------------------------------------------------------
__global__ void scatter_fb(const float* __restrict__ feat,
                           const unsigned int* __restrict__ idxrank,
                           float* __restrict__ out) {
    const int n = blockIdx.x * 256 + threadIdx.x;
    const int b = blockIdx.y;
    if (n >= NPTS) return;
    const int idx = (int)(idxrank[(size_t)b * NPTS + n] >> 16);
    const float* fb = feat + (size_t)b * NC * NPTS + n;
    float* ob = out + (size_t)b * NC * NVOX + idx;
#pragma unroll 4
    for (int c = 0; c < NC; ++c)
        atomicAdd(ob + (size_t)c * NVOX, fb[(size_t)c * NPTS]);
}

__global__ void div_fb(float* __restrict__ out, const int* __restrict__ counts) {
    const int t = blockIdx.x * blockDim.x + threadIdx.x;
    const int b = t >> 15;
    const int v = t & (NVOX - 1);
    const float cnt = fmaxf((float)counts[t], 1.f);
    float* ob = out + (size_t)b * NC * NVOX + v;
#pragma unroll 8
    for (int c = 0; c < NC; ++c)
        ob[(size_t)c * NVOX] /= cnt;
}

// ---------------------------------------------------------------------------
template <int CH>
static void run_passes(const float* feat, unsigned int* idxrank, int* offsets,
                       int* counts, unsigned short* fS, float* out,
                       hipStream_t stream) {
    for (int c0 = 0; c0 < NC; c0 += CH) {
        permute_kernel<CH><<<dim3(NTILE, NB), 256, 0, stream>>>(
            feat, idxrank, offsets, fS, c0);
        gather_kernel<CH><<<dim3(NVOX / 64, NB), 512, 0, stream>>>(
            fS, offsets, counts, out, c0);
    }
}

extern "C" void kernel_launch(void* const* d_in, const int* in_sizes, int n_in,
                              void* d_out, int out_size, void* d_ws, size_t ws_size,
                              hipStream_t stream) {
    const float* feat   = (const float*)d_in[0];  // [8,64,100000]
    const float* coords = (const float*)d_in[1];  // [8,3,100000]

    float* out      = (float*)d_out;                 // [8,64,32,32,32]
    float* norm_out = out + (size_t)NB * NC * NVOX;  // [8,3,100000]

    float*          ws_sum  = (float*)d_ws + SUM_OFF;
    unsigned int*   ws_rad  = (unsigned int*)d_ws + RAD_OFF;
    int*            counts  = (int*)d_ws + CNT_OFF;
    int*            offsets = (int*)d_ws + OFF_OFF;
    unsigned int*   idxrank = (unsigned int*)d_ws + IR_OFF;
    unsigned short* fS      = (unsigned short*)((int*)d_ws + FS_OFF);

    // largest channel chunk that fits the workspace (bf16 featS)
    int CH = 0;
    for (int ch = 64; ch >= 2; ch >>= 1) {
        const size_t need = (size_t)FS_OFF * 4 + (size_t)NB * NPTS * ch * 2;
        if (ws_size >= need) { CH = ch; break; }
    }
    if (CH == 32) CH = 16;   // no 32-wide template; use 16

    hipMemsetAsync(d_ws, 0, ((size_t)CNT_OFF + (size_t)NB * NVOX) * 4, stream);

    sum_kernel<<<dim3(32, NB), 256, 0, stream>>>(coords, ws_sum);
    rad_kernel<<<dim3(32, NB), 256, 0, stream>>>(coords, ws_sum, ws_rad);
    index_kernel<<<dim3(NTILE, NB), 256, 0, stream>>>(
        coords, ws_sum, ws_rad, norm_out, idxrank, counts);

    if (CH == 0) {
        hipMemsetAsync(d_out, 0, (size_t)NB * NC * NVOX * 4, stream);
        scatter_fb<<<dim3(NTILE, NB), 256, 0, stream>>>(feat, idxrank, out);
        div_fb<<<dim3(NB * NVOX / 256), 256, 0, stream>>>(out, counts);
        return;
    }

    scan_kernel<<<dim3(NB), 1024, 0, stream>>>(counts, offsets);

    if (CH == 64) {
        permute64_kernel<<<dim3(NTILE64, NB), 256, 0, stream>>>(
            feat, idxrank, offsets, fS);
        gather64_kernel<<<dim3(NVOX / 64, NB), 512, 0, stream>>>(
            fS, offsets, counts, out);
    } else {
        switch (CH) {
            case 16: run_passes<16>(feat, idxrank, offsets, counts, fS, out, stream); break;
            case 8:  run_passes<8>(feat, idxrank, offsets, counts, fS, out, stream); break;
            case 4:  run_passes<4>(feat, idxrank, offsets, counts, fS, out, stream); break;
            default: run_passes<2>(feat, idxrank, offsets, counts, fS, out, stream); break;
        }
    }
}